// Round 1
// baseline (24.041 us; speedup 1.0000x reference)
//
#include <hip/hip_runtime.h>
#include <math.h>

#define NPIX   25600   // 160*160
#define CCH    8
#define NPARAM 153
#define NINST  100

// Kernel 1: tanh all params once (15300 elements) into workspace.
__global__ __launch_bounds__(256) void tanh_params_kernel(
    const float* __restrict__ params, float* __restrict__ out, int n)
{
    int i = blockIdx.x * blockDim.x + threadIdx.x;
    if (i < n) out[i] = tanhf(params[i]);
}

// Kernel 2: per-instance 3-layer MLP over all pixels.
// grid = (NPIX/(256*4), NINST); blockIdx.y = instance -> params are
// wave-uniform -> scalar loads (SGPR operands for the FMAs).
__global__ __launch_bounds__(256) void mask_head_kernel(
    const float* __restrict__ feats,   // [8][160][160]
    const float* __restrict__ P_all,   // [100][153] tanh'd
    float* __restrict__ out)           // [100][160][160]
{
    const int n = blockIdx.y;
    const float* __restrict__ P = P_all + n * NPARAM;
    const int pix = (blockIdx.x * blockDim.x + threadIdx.x) * 4;

    // Load 4 pixels x 8 channels of the shared feature map.
    float4 x[CCH];
#pragma unroll
    for (int c = 0; c < CCH; ++c)
        x[c] = *reinterpret_cast<const float4*>(feats + c * NPIX + pix);

    // Layer 1: y[o] = relu(sum_c x[c] * w0[o][c] + b0[o])
    float4 y[CCH];
#pragma unroll
    for (int o = 0; o < CCH; ++o) {
        const float b = P[136 + o];
        float4 acc = make_float4(b, b, b, b);
#pragma unroll
        for (int c = 0; c < CCH; ++c) {
            const float w = P[o * 8 + c];
            acc.x = fmaf(x[c].x, w, acc.x);
            acc.y = fmaf(x[c].y, w, acc.y);
            acc.z = fmaf(x[c].z, w, acc.z);
            acc.w = fmaf(x[c].w, w, acc.w);
        }
        acc.x = fmaxf(acc.x, 0.0f);
        acc.y = fmaxf(acc.y, 0.0f);
        acc.z = fmaxf(acc.z, 0.0f);
        acc.w = fmaxf(acc.w, 0.0f);
        y[o] = acc;
    }

    // Layer 2: z[o] = relu(sum_c y[c] * w1[o][c] + b1[o])  (reuse x[] regs)
#pragma unroll
    for (int o = 0; o < CCH; ++o) {
        const float b = P[144 + o];
        float4 acc = make_float4(b, b, b, b);
#pragma unroll
        for (int c = 0; c < CCH; ++c) {
            const float w = P[64 + o * 8 + c];
            acc.x = fmaf(y[c].x, w, acc.x);
            acc.y = fmaf(y[c].y, w, acc.y);
            acc.z = fmaf(y[c].z, w, acc.z);
            acc.w = fmaf(y[c].w, w, acc.w);
        }
        acc.x = fmaxf(acc.x, 0.0f);
        acc.y = fmaxf(acc.y, 0.0f);
        acc.z = fmaxf(acc.z, 0.0f);
        acc.w = fmaxf(acc.w, 0.0f);
        x[o] = acc;
    }

    // Layer 3: s = sum_c z[c] * w2[c] + b2 ; out = sigmoid(s)
    const float b2 = P[152];
    float4 s = make_float4(b2, b2, b2, b2);
#pragma unroll
    for (int c = 0; c < CCH; ++c) {
        const float w = P[128 + c];
        s.x = fmaf(x[c].x, w, s.x);
        s.y = fmaf(x[c].y, w, s.y);
        s.z = fmaf(x[c].z, w, s.z);
        s.w = fmaf(x[c].w, w, s.w);
    }

    float4 r;
    r.x = 1.0f / (1.0f + __expf(-s.x));
    r.y = 1.0f / (1.0f + __expf(-s.y));
    r.z = 1.0f / (1.0f + __expf(-s.z));
    r.w = 1.0f / (1.0f + __expf(-s.w));

    *reinterpret_cast<float4*>(out + n * NPIX + pix) = r;
}

extern "C" void kernel_launch(void* const* d_in, const int* in_sizes, int n_in,
                              void* d_out, int out_size, void* d_ws, size_t ws_size,
                              hipStream_t stream) {
    const float* feats  = (const float*)d_in[0];   // (1,8,160,160) fp32
    const float* params = (const float*)d_in[1];   // (100,153) fp32
    // d_in[2] det_bbox, d_in[3] fpn_levels: unused by the reference.
    float* out = (float*)d_out;                    // (100,160,160) fp32
    float* p_tanh = (float*)d_ws;                  // 15300 floats

    const int nP = NINST * NPARAM;
    tanh_params_kernel<<<(nP + 255) / 256, 256, 0, stream>>>(params, p_tanh, nP);

    dim3 grid(NPIX / (256 * 4), NINST);  // (25, 100)
    mask_head_kernel<<<grid, 256, 0, stream>>>(feats, p_tanh, out);
}

// Round 2
// 21.390 us; speedup vs baseline: 1.1239x; 1.1239x over previous
//
#include <hip/hip_runtime.h>
#include <math.h>

#define NPIX   25600   // 160*160
#define CCH    8
#define NPARAM 153
#define NINST  100

typedef float f2 __attribute__((ext_vector_type(2)));

__device__ __forceinline__ float fast_tanh(float v) {
    // tanh(x) = 1 - 2/(e^{2x}+1); v_exp_f32 + v_rcp_f32, ~6 instrs.
    float e = __expf(2.0f * v);
    return 1.0f - 2.0f * __builtin_amdgcn_rcpf(e + 1.0f);
}

__device__ __forceinline__ float fast_sigmoid(float s) {
    return __builtin_amdgcn_rcpf(1.0f + __expf(-s));
}

// Kernel 1: tanh all params once (15300 elements) into workspace.
__global__ __launch_bounds__(256) void tanh_params_kernel(
    const float* __restrict__ params, float* __restrict__ out, int n)
{
    int i = blockIdx.x * blockDim.x + threadIdx.x;
    if (i < n) out[i] = fast_tanh(params[i]);
}

// Kernel 2: per-instance 3-layer MLP over all pixels, packed-fp32 math.
// grid = (25, 100); blockIdx.y = instance -> param loads are wave-uniform
// (s_load -> SGPR operands). Each thread: 4 pixels as 2x f2 vectors so the
// backend emits v_pk_fma_f32 / v_pk_max_f32 (2 FMA per lane per instr).
__global__ __launch_bounds__(256) void mask_head_kernel(
    const float* __restrict__ feats,   // [8][160][160]
    const float* __restrict__ P_all,   // [100][153] tanh'd
    float* __restrict__ out)           // [100][160][160]
{
    const int n = blockIdx.y;
    const float* __restrict__ P = P_all + n * NPARAM;
    const int pix = (blockIdx.x * blockDim.x + threadIdx.x) * 4;

    // Load 4 pixels x 8 channels of the shared feature map.
    f2 x0[CCH], x1[CCH];
#pragma unroll
    for (int c = 0; c < CCH; ++c) {
        const float4 v = *reinterpret_cast<const float4*>(feats + c * NPIX + pix);
        x0[c] = (f2){v.x, v.y};
        x1[c] = (f2){v.z, v.w};
    }

    const f2 zero = (f2){0.0f, 0.0f};

    // Layer 1: y[o] = relu(sum_c x[c]*w0[o][c] + b0[o])
    f2 y0[CCH], y1[CCH];
#pragma unroll
    for (int o = 0; o < CCH; ++o) {
        const float b = P[136 + o];
        f2 a0 = (f2){b, b}, a1 = (f2){b, b};
#pragma unroll
        for (int c = 0; c < CCH; ++c) {
            const float w = P[o * 8 + c];
            const f2 wv = (f2){w, w};
            a0 = __builtin_elementwise_fma(x0[c], wv, a0);
            a1 = __builtin_elementwise_fma(x1[c], wv, a1);
        }
        y0[o] = __builtin_elementwise_max(a0, zero);
        y1[o] = __builtin_elementwise_max(a1, zero);
    }

    // Layer 2: z[o] = relu(sum_c y[c]*w1[o][c] + b1[o])  (reuse x[] regs)
#pragma unroll
    for (int o = 0; o < CCH; ++o) {
        const float b = P[144 + o];
        f2 a0 = (f2){b, b}, a1 = (f2){b, b};
#pragma unroll
        for (int c = 0; c < CCH; ++c) {
            const float w = P[64 + o * 8 + c];
            const f2 wv = (f2){w, w};
            a0 = __builtin_elementwise_fma(y0[c], wv, a0);
            a1 = __builtin_elementwise_fma(y1[c], wv, a1);
        }
        x0[o] = __builtin_elementwise_max(a0, zero);
        x1[o] = __builtin_elementwise_max(a1, zero);
    }

    // Layer 3: s = sum_c z[c]*w2[c] + b2 ; out = sigmoid(s)
    const float b2 = P[152];
    f2 s0 = (f2){b2, b2}, s1 = (f2){b2, b2};
#pragma unroll
    for (int c = 0; c < CCH; ++c) {
        const float w = P[128 + c];
        const f2 wv = (f2){w, w};
        s0 = __builtin_elementwise_fma(x0[c], wv, s0);
        s1 = __builtin_elementwise_fma(x1[c], wv, s1);
    }

    float4 r;
    r.x = fast_sigmoid(s0.x);
    r.y = fast_sigmoid(s0.y);
    r.z = fast_sigmoid(s1.x);
    r.w = fast_sigmoid(s1.y);

    *reinterpret_cast<float4*>(out + n * NPIX + pix) = r;
}

extern "C" void kernel_launch(void* const* d_in, const int* in_sizes, int n_in,
                              void* d_out, int out_size, void* d_ws, size_t ws_size,
                              hipStream_t stream) {
    const float* feats  = (const float*)d_in[0];   // (1,8,160,160) fp32
    const float* params = (const float*)d_in[1];   // (100,153) fp32
    // d_in[2] det_bbox, d_in[3] fpn_levels: unused by the reference.
    float* out = (float*)d_out;                    // (100,160,160) fp32
    float* p_tanh = (float*)d_ws;                  // 15300 floats

    const int nP = NINST * NPARAM;
    tanh_params_kernel<<<(nP + 255) / 256, 256, 0, stream>>>(params, p_tanh, nP);

    dim3 grid(NPIX / (256 * 4), NINST);  // (25, 100)
    mask_head_kernel<<<grid, 256, 0, stream>>>(feats, p_tanh, out);
}

// Round 3
// 16.718 us; speedup vs baseline: 1.4381x; 1.2795x over previous
//
#include <hip/hip_runtime.h>
#include <math.h>

#define NPIX   25600   // 160*160
#define CCH    8
#define NPARAM 153
#define NINST  100

typedef float f2 __attribute__((ext_vector_type(2)));

__device__ __forceinline__ float fast_tanh(float v) {
    // tanh(x) = 1 - 2/(e^{2x}+1); v_exp_f32 + v_rcp_f32.
    float e = __expf(2.0f * v);
    return 1.0f - 2.0f * __builtin_amdgcn_rcpf(e + 1.0f);
}

__device__ __forceinline__ float fast_sigmoid(float s) {
    return __builtin_amdgcn_rcpf(1.0f + __expf(-s));
}

// Fused kernel: per-block tanh of this instance's 153 params into LDS,
// then 3-layer MLP on 4 pixels/thread with packed-fp32 math.
// grid = (25, 100); weights read as broadcast float4 LDS loads (no conflicts).
__global__ __launch_bounds__(256) void mask_head_fused_kernel(
    const float* __restrict__ feats,    // [8][160][160]
    const float* __restrict__ params,   // [100][153] raw
    float* __restrict__ out)            // [100][160][160]
{
    __shared__ float Pt[NPARAM + 3];    // tanh'd params (pad to float4 multiple)

    const int n   = blockIdx.y;
    const int tid = threadIdx.x;
    const int pix = (blockIdx.x * blockDim.x + tid) * 4;

    // Issue feature loads first so they are in flight during tanh + barrier.
    f2 x0[CCH], x1[CCH];
#pragma unroll
    for (int c = 0; c < CCH; ++c) {
        const float4 v = *reinterpret_cast<const float4*>(feats + c * NPIX + pix);
        x0[c] = (f2){v.x, v.y};
        x1[c] = (f2){v.z, v.w};
    }

    // tanh this instance's params into LDS (threads 0..152).
    if (tid < NPARAM)
        Pt[tid] = fast_tanh(params[n * NPARAM + tid]);
    __syncthreads();

    const f2 zero = (f2){0.0f, 0.0f};

    // Layer 1: y[o] = relu(sum_c x[c]*w0[o][c] + b0[o])
    f2 y0[CCH], y1[CCH];
#pragma unroll
    for (int o = 0; o < CCH; ++o) {
        const float4 wa = *reinterpret_cast<const float4*>(&Pt[o * 8]);
        const float4 wb = *reinterpret_cast<const float4*>(&Pt[o * 8 + 4]);
        const float b = Pt[136 + o];
        f2 a0 = (f2){b, b}, a1 = (f2){b, b};
        const float w[8] = {wa.x, wa.y, wa.z, wa.w, wb.x, wb.y, wb.z, wb.w};
#pragma unroll
        for (int c = 0; c < CCH; ++c) {
            const f2 wv = (f2){w[c], w[c]};
            a0 = __builtin_elementwise_fma(x0[c], wv, a0);
            a1 = __builtin_elementwise_fma(x1[c], wv, a1);
        }
        y0[o] = __builtin_elementwise_max(a0, zero);
        y1[o] = __builtin_elementwise_max(a1, zero);
    }

    // Layer 2: z[o] = relu(sum_c y[c]*w1[o][c] + b1[o])  (reuse x[] regs)
#pragma unroll
    for (int o = 0; o < CCH; ++o) {
        const float4 wa = *reinterpret_cast<const float4*>(&Pt[64 + o * 8]);
        const float4 wb = *reinterpret_cast<const float4*>(&Pt[64 + o * 8 + 4]);
        const float b = Pt[144 + o];
        f2 a0 = (f2){b, b}, a1 = (f2){b, b};
        const float w[8] = {wa.x, wa.y, wa.z, wa.w, wb.x, wb.y, wb.z, wb.w};
#pragma unroll
        for (int c = 0; c < CCH; ++c) {
            const f2 wv = (f2){w[c], w[c]};
            a0 = __builtin_elementwise_fma(y0[c], wv, a0);
            a1 = __builtin_elementwise_fma(y1[c], wv, a1);
        }
        x0[o] = __builtin_elementwise_max(a0, zero);
        x1[o] = __builtin_elementwise_max(a1, zero);
    }

    // Layer 3: s = sum_c z[c]*w2[c] + b2 ; out = sigmoid(s)
    const float4 wa = *reinterpret_cast<const float4*>(&Pt[128]);
    const float4 wb = *reinterpret_cast<const float4*>(&Pt[132]);
    const float b2 = Pt[152];
    const float w2[8] = {wa.x, wa.y, wa.z, wa.w, wb.x, wb.y, wb.z, wb.w};
    f2 s0 = (f2){b2, b2}, s1 = (f2){b2, b2};
#pragma unroll
    for (int c = 0; c < CCH; ++c) {
        const f2 wv = (f2){w2[c], w2[c]};
        s0 = __builtin_elementwise_fma(x0[c], wv, s0);
        s1 = __builtin_elementwise_fma(x1[c], wv, s1);
    }

    float4 r;
    r.x = fast_sigmoid(s0.x);
    r.y = fast_sigmoid(s0.y);
    r.z = fast_sigmoid(s1.x);
    r.w = fast_sigmoid(s1.y);

    *reinterpret_cast<float4*>(out + n * NPIX + pix) = r;
}

extern "C" void kernel_launch(void* const* d_in, const int* in_sizes, int n_in,
                              void* d_out, int out_size, void* d_ws, size_t ws_size,
                              hipStream_t stream) {
    const float* feats  = (const float*)d_in[0];   // (1,8,160,160) fp32
    const float* params = (const float*)d_in[1];   // (100,153) fp32
    // d_in[2] det_bbox, d_in[3] fpn_levels: unused by the reference.
    float* out = (float*)d_out;                    // (100,160,160) fp32

    dim3 grid(NPIX / (256 * 4), NINST);  // (25, 100)
    mask_head_fused_kernel<<<grid, 256, 0, stream>>>(feats, params, out);
}

// Round 4
// 16.492 us; speedup vs baseline: 1.4578x; 1.0137x over previous
//
#include <hip/hip_runtime.h>
#include <math.h>

#define NPIX   25600   // 160*160
#define CCH    8
#define NPARAM 153
#define NINST  100
#define NI_PER_BLK 2

typedef float f2 __attribute__((ext_vector_type(2)));

__device__ __forceinline__ float fast_tanh(float v) {
    // tanh(x) = 1 - 2/(e^{2x}+1); v_exp_f32 + v_rcp_f32.
    float e = __expf(2.0f * v);
    return 1.0f - 2.0f * __builtin_amdgcn_rcpf(e + 1.0f);
}

__device__ __forceinline__ float fast_sigmoid(float s) {
    return __builtin_amdgcn_rcpf(1.0f + __expf(-s));
}

// Fused kernel, 2 instances per block: feature loads + tanh prologue + block
// ramp amortized 2x. grid = (25, 50); 4 pixels/thread; packed-fp32 math;
// all weight reads are broadcast LDS loads (conflict-free).
__global__ __launch_bounds__(256) void mask_head_fused2_kernel(
    const float* __restrict__ feats,    // [8][160][160]
    const float* __restrict__ params,   // [100][153] raw
    float* __restrict__ out)            // [100][160][160]
{
    __shared__ float Pt[NI_PER_BLK][NPARAM + 3];

    const int tid = threadIdx.x;
    const int n0  = blockIdx.y * NI_PER_BLK;
    const int pix = (blockIdx.x * blockDim.x + tid) * 4;

    // Issue feature loads first so they are in flight during tanh + barrier.
    f2 x0[CCH], x1[CCH];
#pragma unroll
    for (int c = 0; c < CCH; ++c) {
        const float4 v = *reinterpret_cast<const float4*>(feats + c * NPIX + pix);
        x0[c] = (f2){v.x, v.y};
        x1[c] = (f2){v.z, v.w};
    }

    // tanh both instances' params into LDS (threads 0..152, 2 each).
    if (tid < NPARAM) {
        Pt[0][tid] = fast_tanh(params[n0 * NPARAM + tid]);
        Pt[1][tid] = fast_tanh(params[(n0 + 1) * NPARAM + tid]);
    }
    __syncthreads();

    const f2 zero = (f2){0.0f, 0.0f};

#pragma unroll
    for (int i = 0; i < NI_PER_BLK; ++i) {
        const float* __restrict__ P = Pt[i];

        // Layer 1: y[o] = relu(sum_c x[c]*w0[o][c] + b0[o])
        f2 y0[CCH], y1[CCH];
#pragma unroll
        for (int o = 0; o < CCH; ++o) {
            const float b = P[136 + o];
            f2 a0 = (f2){b, b}, a1 = (f2){b, b};
#pragma unroll
            for (int c = 0; c < CCH; ++c) {
                const float w = P[o * 8 + c];
                const f2 wv = (f2){w, w};
                a0 = __builtin_elementwise_fma(x0[c], wv, a0);
                a1 = __builtin_elementwise_fma(x1[c], wv, a1);
            }
            y0[o] = __builtin_elementwise_max(a0, zero);
            y1[o] = __builtin_elementwise_max(a1, zero);
        }

        // Layer 2: z[o] = relu(sum_c y[c]*w1[o][c] + b1[o])
        f2 z0[CCH], z1[CCH];
#pragma unroll
        for (int o = 0; o < CCH; ++o) {
            const float b = P[144 + o];
            f2 a0 = (f2){b, b}, a1 = (f2){b, b};
#pragma unroll
            for (int c = 0; c < CCH; ++c) {
                const float w = P[64 + o * 8 + c];
                const f2 wv = (f2){w, w};
                a0 = __builtin_elementwise_fma(y0[c], wv, a0);
                a1 = __builtin_elementwise_fma(y1[c], wv, a1);
            }
            z0[o] = __builtin_elementwise_max(a0, zero);
            z1[o] = __builtin_elementwise_max(a1, zero);
        }

        // Layer 3: s = sum_c z[c]*w2[c] + b2 ; out = sigmoid(s)
        const float b2 = P[152];
        f2 s0 = (f2){b2, b2}, s1 = (f2){b2, b2};
#pragma unroll
        for (int c = 0; c < CCH; ++c) {
            const float w = P[128 + c];
            const f2 wv = (f2){w, w};
            s0 = __builtin_elementwise_fma(z0[c], wv, s0);
            s1 = __builtin_elementwise_fma(z1[c], wv, s1);
        }

        float4 r;
        r.x = fast_sigmoid(s0.x);
        r.y = fast_sigmoid(s0.y);
        r.z = fast_sigmoid(s1.x);
        r.w = fast_sigmoid(s1.y);

        *reinterpret_cast<float4*>(out + (n0 + i) * NPIX + pix) = r;
    }
}

extern "C" void kernel_launch(void* const* d_in, const int* in_sizes, int n_in,
                              void* d_out, int out_size, void* d_ws, size_t ws_size,
                              hipStream_t stream) {
    const float* feats  = (const float*)d_in[0];   // (1,8,160,160) fp32
    const float* params = (const float*)d_in[1];   // (100,153) fp32
    // d_in[2] det_bbox, d_in[3] fpn_levels: unused by the reference.
    float* out = (float*)d_out;                    // (100,160,160) fp32

    dim3 grid(NPIX / (256 * 4), NINST / NI_PER_BLK);  // (25, 50)
    mask_head_fused2_kernel<<<grid, 256, 0, stream>>>(feats, params, out);
}